// Round 1
// baseline (13353.670 us; speedup 1.0000x reference)
//
#include <hip/hip_runtime.h>

typedef short bf16x8 __attribute__((ext_vector_type(8)));
typedef float f32x4 __attribute__((ext_vector_type(4)));

#define HID   1024
#define BATCH 8
#define TLEN  256
#define VOCABN 50257
#define GATES 4096   // 4*HID
#define M_ROWS 2048  // B*T

__device__ __forceinline__ unsigned short f2bf(float x) {
  unsigned int u = __float_as_uint(x);
  unsigned int r = (u + 0x7fffu + ((u >> 16) & 1u)) >> 16;
  return (unsigned short)r;
}

__global__ void conv_f32_bf16(const float* __restrict__ src,
                              unsigned short* __restrict__ dst, int n4) {
  int i = blockIdx.x * 256 + threadIdx.x;
  if (i >= n4) return;
  float4 v = ((const float4*)src)[i];
  ushort4 o;
  o.x = f2bf(v.x); o.y = f2bf(v.y); o.z = f2bf(v.z); o.w = f2bf(v.w);
  ((ushort4*)dst)[i] = o;
}

__global__ void bias_sum_kernel(const float* __restrict__ a,
                                const float* __restrict__ b,
                                float* __restrict__ o) {
  int i = blockIdx.x * 256 + threadIdx.x;
  if (i < GATES) o[i] = a[i] + b[i];
}

__global__ void init_flags(unsigned* __restrict__ f) { f[threadIdx.x] = 0u; }

// C[m][n] = sum_k A[m,k]*B[n,k] + bias[n].  A,B bf16 K-major, C fp32.
// tokens!=nullptr => A row m is table row tokens[m] (embedding gather).
#define GSTR 72  // LDS row stride in bf16 (64 data + 8 pad) -> conflict-free b128 frag reads

__global__ __launch_bounds__(256) void gemm_bt_bf16(
    const unsigned short* __restrict__ A, const unsigned short* __restrict__ Bm,
    const float* __restrict__ bias, float* __restrict__ C,
    const int* __restrict__ tokens, int ldc, int Nreal) {
  __shared__ unsigned short As[128 * GSTR];
  __shared__ unsigned short Bs[128 * GSTR];
  const int tid = threadIdx.x;
  const int m0 = blockIdx.x * 128;
  const int n0 = blockIdx.y * 128;
  const int wid = tid >> 6, lane = tid & 63;
  const int wm = (wid & 1) * 64, wn = (wid >> 1) * 64;
  const int lm = lane & 15, quad = lane >> 4;

  f32x4 acc[4][4];
  #pragma unroll
  for (int i = 0; i < 4; ++i)
    #pragma unroll
    for (int j = 0; j < 4; ++j) acc[i][j] = (f32x4){0.f, 0.f, 0.f, 0.f};

  for (int k0 = 0; k0 < HID; k0 += 64) {
    #pragma unroll
    for (int it = 0; it < 4; ++it) {           // 1024 16B-chunks per tile, 256 thr
      int c = tid + it * 256;
      int row = c >> 3, ch = c & 7;
      int gm = m0 + row;
      int arow = tokens ? tokens[gm] : gm;
      uint4 v = *(const uint4*)(A + (size_t)arow * HID + k0 + ch * 8);
      *(uint4*)&As[row * GSTR + ch * 8] = v;
      int gn = n0 + row;
      uint4 w = make_uint4(0u, 0u, 0u, 0u);
      if (gn < Nreal) w = *(const uint4*)(Bm + (size_t)gn * HID + k0 + ch * 8);
      *(uint4*)&Bs[row * GSTR + ch * 8] = w;
    }
    __syncthreads();
    #pragma unroll
    for (int kk = 0; kk < 2; ++kk) {
      bf16x8 af[4], bfr[4];
      #pragma unroll
      for (int i = 0; i < 4; ++i)
        af[i] = *(const bf16x8*)&As[(wm + i * 16 + lm) * GSTR + kk * 32 + quad * 8];
      #pragma unroll
      for (int j = 0; j < 4; ++j)
        bfr[j] = *(const bf16x8*)&Bs[(wn + j * 16 + lm) * GSTR + kk * 32 + quad * 8];
      #pragma unroll
      for (int i = 0; i < 4; ++i)
        #pragma unroll
        for (int j = 0; j < 4; ++j)
          acc[i][j] = __builtin_amdgcn_mfma_f32_16x16x32_bf16(af[i], bfr[j], acc[i][j], 0, 0, 0);
    }
    __syncthreads();
  }
  // D layout: col = lane&15, row = quad*4 + reg  [measured m89/m91]
  #pragma unroll
  for (int i = 0; i < 4; ++i) {
    #pragma unroll
    for (int j = 0; j < 4; ++j) {
      #pragma unroll
      for (int r = 0; r < 4; ++r) {
        int gm = m0 + wm + i * 16 + quad * 4 + r;
        int gn = n0 + wn + j * 16 + lm;
        if (gn < Nreal)
          C[(size_t)gm * ldc + gn] = acc[i][j][r] + (bias ? bias[gn] : 0.f);
      }
    }
  }
}

// ---------------------------------------------------------------------------
// Persistent LSTM: all 256 timesteps in ONE cooperative kernel.
// 256 blocks x 256 threads; block owns 4 cells (16 w_hh rows) held in
// REGISTERS (wreg[4][16] per thread, k split across 64 lanes) for the whole
// sequence. h ping-pongs through global in transposed [j][b] layout.
// Cross-step sync: per-block flag barrier with device-scope atomics/fences.
// ---------------------------------------------------------------------------
__device__ __forceinline__ void gbar(unsigned* __restrict__ flags, unsigned gen) {
  __syncthreads();                 // all waves drained (vmcnt0 at barrier)
  if (threadIdx.x == 0) {
    __threadfence();               // writeback this XCD's L2 -> coherence point
    __hip_atomic_store(&flags[blockIdx.x], gen, __ATOMIC_RELEASE,
                       __HIP_MEMORY_SCOPE_AGENT);
  }
  // 256 threads each poll one block's flag (flags are monotone generations)
  while (__hip_atomic_load(&flags[threadIdx.x], __ATOMIC_ACQUIRE,
                           __HIP_MEMORY_SCOPE_AGENT) < gen) {}
  __threadfence();                 // invalidate stale lines before reading h
  __syncthreads();
}

__global__ __launch_bounds__(256) void lstm_persistent(
    const float* __restrict__ whh, const float* __restrict__ xproj,
    float* __restrict__ hbuf, unsigned short* __restrict__ adec,
    float* __restrict__ out_hc, unsigned* __restrict__ flags) {
  // smem dual-use (barrier-separated): phase A = h staged [k][b] pad-9
  // (1024*9 floats); phase B = partial-sum transpose [32][257] (8224 floats).
  __shared__ float smem[1024 * 9];
  __shared__ float gsum[16][8];
  const int tid = threadIdx.x;
  const int lane = tid & 63;       // k-segment: this lane covers k = kk*64+lane
  const int rq = tid >> 6;         // wave id = cell-within-block 0..3
  const int j0 = blockIdx.x * 4;   // first hidden cell of this block

  // persistent weights: rows (gate i, cell rq), element k = kk*64+lane
  float wreg[4][16];
  #pragma unroll
  for (int i = 0; i < 4; ++i)
    #pragma unroll
    for (int kk = 0; kk < 16; ++kk)
      wreg[i][kk] = whh[(size_t)(i * HID + j0 + rq) * HID + kk * 64 + lane];

  // reduce-phase mapping (tid<128): output (gate ui, cell uq, batch ub)
  const int ur = tid >> 3, ub = tid & 7;
  const int ui = ur & 3, uq = ur >> 2;
  float creg = 0.f;                // c-state for tid<32 update threads

  for (int t = 0; t < TLEN; ++t) {
    // prefetch this thread's xproj term (latency hides under stage+compute)
    float xp = 0.f;
    if (tid < 128)
      xp = xproj[(size_t)(ub * TLEN + t) * GATES + ui * HID + j0 + uq];

    // stage h_t (global transposed [j][b]) into LDS [k][b] stride 9
    const float4* hsrc = (const float4*)(hbuf + (size_t)(t & 1) * (BATCH * HID));
    #pragma unroll
    for (int it = 0; it < 8; ++it) {
      int idx = tid + it * 256;                 // 0..2047 float4s
      float4 v = make_float4(0.f, 0.f, 0.f, 0.f);
      if (t > 0) v = hsrc[idx];
      int k = idx >> 1, half = idx & 1;
      *(float4*)&smem[k * 9 + half * 4] = v;
    }
    __syncthreads();

    // 4 rows x 8 batches register outer product, k = kk*64+lane
    float acc[4][8];
    #pragma unroll
    for (int i = 0; i < 4; ++i)
      #pragma unroll
      for (int b = 0; b < 8; ++b) acc[i][b] = 0.f;
    #pragma unroll
    for (int kk = 0; kk < 16; ++kk) {
      const float* hp = &smem[(kk * 64 + lane) * 9];
      float4 ha = *(const float4*)hp;
      float4 hb = *(const float4*)(hp + 4);
      #pragma unroll
      for (int i = 0; i < 4; ++i) {
        float w = wreg[i][kk];
        acc[i][0] += w * ha.x; acc[i][1] += w * ha.y;
        acc[i][2] += w * ha.z; acc[i][3] += w * ha.w;
        acc[i][4] += w * hb.x; acc[i][5] += w * hb.y;
        acc[i][6] += w * hb.z; acc[i][7] += w * hb.w;
      }
    }
    __syncthreads();   // all h reads done before smem is reused for partials

    // column-major partial store: red[j][tid], j = gate*8+b  (stride 257:
    // conflict-free scalar access both directions)
    #pragma unroll
    for (int i = 0; i < 4; ++i)
      #pragma unroll
      for (int b = 0; b < 8; ++b)
        smem[(size_t)(i * 8 + b) * 257 + tid] = acc[i][b];
    __syncthreads();

    if (tid < 128) {
      const float* rp = &smem[(size_t)(ui * 8 + ub) * 257 + uq * 64];
      float s0 = 0.f, s1 = 0.f, s2 = 0.f, s3 = 0.f;
      #pragma unroll
      for (int c = 0; c < 16; ++c) {
        s0 += rp[c * 4 + 0]; s1 += rp[c * 4 + 1];
        s2 += rp[c * 4 + 2]; s3 += rp[c * 4 + 3];
      }
      gsum[ur][ub] = (s0 + s1) + (s2 + s3) + xp;
    }
    __syncthreads();

    if (tid < 32) {
      const int cl = tid >> 3, bb = tid & 7, j = j0 + cl;
      float gi = gsum[cl * 4 + 0][bb];
      float gf = gsum[cl * 4 + 1][bb];
      float gg = gsum[cl * 4 + 2][bb];
      float go = gsum[cl * 4 + 3][bb];
      float si = 1.f / (1.f + __expf(-gi));
      float sf = 1.f / (1.f + __expf(-gf));
      float tg = tanhf(gg);
      float so = 1.f / (1.f + __expf(-go));
      float c = sf * creg + si * tg;            // t==0: creg==0
      creg = c;
      float h = so * tanhf(c);
      // transposed h for next step: [j][b], 32 consecutive dwords per block
      hbuf[(size_t)((t + 1) & 1) * (BATCH * HID) + j * 8 + bb] = h;
      adec[(size_t)(bb * TLEN + t) * HID + j] = f2bf(h);
      if (t == TLEN - 1) {
        out_hc[bb * HID + j] = h;                  // hT
        out_hc[BATCH * HID + bb * HID + j] = c;    // cT
      }
    }
    gbar(flags, (unsigned)(t + 1));
  }
}

// In-place log-softmax over rows of [2048][50257]
__global__ __launch_bounds__(512) void logsoftmax_rows(float* __restrict__ data) {
  const int row = blockIdx.x;
  float* p = data + (size_t)row * VOCABN;
  const int tid = threadIdx.x;
  float m = -INFINITY, l = 0.f;
  for (int i = tid; i < VOCABN; i += 512) {
    float x = p[i];
    float nm = fmaxf(m, x);
    l = l * __expf(m - nm) + __expf(x - nm);
    m = nm;
  }
  #pragma unroll
  for (int off = 32; off > 0; off >>= 1) {
    float m2 = __shfl_down(m, off);
    float l2 = __shfl_down(l, off);
    float nm = fmaxf(m, m2);
    l = l * __expf(m - nm) + l2 * __expf(m2 - nm);
    m = nm;
  }
  __shared__ float sm[8], sl[8];
  if ((tid & 63) == 0) { sm[tid >> 6] = m; sl[tid >> 6] = l; }
  __syncthreads();
  if (tid == 0) {
    m = sm[0]; l = sl[0];
    for (int i2 = 1; i2 < 8; ++i2) {
      float m2 = sm[i2], l2 = sl[i2];
      float nm = fmaxf(m, m2);
      l = l * __expf(m - nm) + l2 * __expf(m2 - nm);
      m = nm;
    }
    sm[0] = m; sl[0] = logf(l);
  }
  __syncthreads();
  float M = sm[0], L = sl[0];
  for (int i = tid; i < VOCABN; i += 512) p[i] = p[i] - M - L;
}

extern "C" void kernel_launch(void* const* d_in, const int* in_sizes, int n_in,
                              void* d_out, int out_size, void* d_ws, size_t ws_size,
                              hipStream_t stream) {
  const int*   x     = (const int*)d_in[0];
  const float* embW  = (const float*)d_in[1];
  const float* w_ih  = (const float*)d_in[2];
  const float* w_hh  = (const float*)d_in[3];
  const float* b_ih  = (const float*)d_in[4];
  const float* b_hh  = (const float*)d_in[5];
  const float* dec_b = (const float*)d_in[6];
  float* out = (float*)d_out;

  // ws carve
  char* ws = (char*)d_ws;
  unsigned short* emb_bf = (unsigned short*)ws;  ws += (size_t)VOCABN * HID * 2;
  unsigned short* wih_bf = (unsigned short*)ws;  ws += (size_t)GATES * HID * 2;
  float* bias_s = (float*)ws;                    ws += (size_t)GATES * 4;
  float* xproj  = (float*)ws;                    ws += (size_t)M_ROWS * GATES * 4;
  unsigned short* adec = (unsigned short*)ws;    ws += (size_t)M_ROWS * HID * 2;
  float* hbuf = (float*)ws;                      ws += (size_t)2 * BATCH * HID * 4;
  unsigned* flags = (unsigned*)ws;               ws += 1024;

  int n4emb = VOCABN * HID / 4;
  conv_f32_bf16<<<(n4emb + 255) / 256, 256, 0, stream>>>(embW, emb_bf, n4emb);
  int n4wih = GATES * HID / 4;
  conv_f32_bf16<<<(n4wih + 255) / 256, 256, 0, stream>>>(w_ih, wih_bf, n4wih);
  bias_sum_kernel<<<16, 256, 0, stream>>>(b_ih, b_hh, bias_s);
  init_flags<<<1, 256, 0, stream>>>(flags);

  // x_proj[bt][g] = emb_W[x[bt]] . w_ih[g] + (b_ih+b_hh)[g]
  gemm_bt_bf16<<<dim3(16, 32), 256, 0, stream>>>(emb_bf, wih_bf, bias_s, xproj,
                                                 x, GATES, GATES);

  // one persistent kernel = entire recurrence
  float* out_hc = out + (size_t)M_ROWS * VOCABN;
  void* kargs[] = {(void*)&w_hh, (void*)&xproj, (void*)&hbuf,
                   (void*)&adec, (void*)&out_hc, (void*)&flags};
  hipError_t ce = hipLaunchCooperativeKernel((void*)lstm_persistent,
                                             dim3(256), dim3(256), kargs, 0, stream);
  if (ce != hipSuccess) {
    // fallback: plain launch; 256 blocks x 256 thr (37KB LDS) = 1 block/CU,
    // naturally co-resident on an idle 256-CU device
    lstm_persistent<<<dim3(256), dim3(256), 0, stream>>>(w_hh, xproj, hbuf,
                                                         adec, out_hc, flags);
  }

  // logits[bt][v] = h[bt] . emb_W[v] + dec_b[v]
  gemm_bt_bf16<<<dim3(16, 393), 256, 0, stream>>>(adec, emb_bf, dec_b, out,
                                                  nullptr, VOCABN, VOCABN);

  logsoftmax_rows<<<2048, 512, 0, stream>>>(out);
}

// Round 2
// 4861.807 us; speedup vs baseline: 2.7466x; 2.7466x over previous
//
#include <hip/hip_runtime.h>

typedef short bf16x8 __attribute__((ext_vector_type(8)));
typedef float f32x4 __attribute__((ext_vector_type(4)));

#define HID   1024
#define BATCH 8
#define TLEN  256
#define VOCABN 50257
#define GATES 4096   // 4*HID
#define M_ROWS 2048  // B*T

__device__ __forceinline__ unsigned short f2bf(float x) {
  unsigned int u = __float_as_uint(x);
  unsigned int r = (u + 0x7fffu + ((u >> 16) & 1u)) >> 16;
  return (unsigned short)r;
}

// ---- agent-scope (cross-XCD coherent) primitives: no fences, no L2 flush ----
__device__ __forceinline__ unsigned agent_load(const unsigned* p) {
  return __hip_atomic_load(p, __ATOMIC_RELAXED, __HIP_MEMORY_SCOPE_AGENT);
}
__device__ __forceinline__ unsigned long long agent_load64(const unsigned long long* p) {
  return __hip_atomic_load(p, __ATOMIC_RELAXED, __HIP_MEMORY_SCOPE_AGENT);
}
__device__ __forceinline__ void agent_store(unsigned* p, unsigned v) {
  __hip_atomic_store(p, v, __ATOMIC_RELAXED, __HIP_MEMORY_SCOPE_AGENT);
}

__global__ void conv_f32_bf16(const float* __restrict__ src,
                              unsigned short* __restrict__ dst, int n4) {
  int i = blockIdx.x * 256 + threadIdx.x;
  if (i >= n4) return;
  float4 v = ((const float4*)src)[i];
  ushort4 o;
  o.x = f2bf(v.x); o.y = f2bf(v.y); o.z = f2bf(v.z); o.w = f2bf(v.w);
  ((ushort4*)dst)[i] = o;
}

__global__ void bias_sum_kernel(const float* __restrict__ a,
                                const float* __restrict__ b,
                                float* __restrict__ o) {
  int i = blockIdx.x * 256 + threadIdx.x;
  if (i < GATES) o[i] = a[i] + b[i];
}

__global__ void init_flags(unsigned* __restrict__ f) {
  f[blockIdx.x * 256 + threadIdx.x] = 0u;
}

// C[m][n] = sum_k A[m,k]*B[n,k] + bias[n].  A,B bf16 K-major, C fp32.
// tokens!=nullptr => A row m is table row tokens[m] (embedding gather).
#define GSTR 72  // LDS row stride in bf16 (64 data + 8 pad) -> conflict-free b128 frag reads

__global__ __launch_bounds__(256) void gemm_bt_bf16(
    const unsigned short* __restrict__ A, const unsigned short* __restrict__ Bm,
    const float* __restrict__ bias, float* __restrict__ C,
    const int* __restrict__ tokens, int ldc, int Nreal) {
  __shared__ unsigned short As[128 * GSTR];
  __shared__ unsigned short Bs[128 * GSTR];
  const int tid = threadIdx.x;
  const int m0 = blockIdx.x * 128;
  const int n0 = blockIdx.y * 128;
  const int wid = tid >> 6, lane = tid & 63;
  const int wm = (wid & 1) * 64, wn = (wid >> 1) * 64;
  const int lm = lane & 15, quad = lane >> 4;

  f32x4 acc[4][4];
  #pragma unroll
  for (int i = 0; i < 4; ++i)
    #pragma unroll
    for (int j = 0; j < 4; ++j) acc[i][j] = (f32x4){0.f, 0.f, 0.f, 0.f};

  for (int k0 = 0; k0 < HID; k0 += 64) {
    #pragma unroll
    for (int it = 0; it < 4; ++it) {           // 1024 16B-chunks per tile, 256 thr
      int c = tid + it * 256;
      int row = c >> 3, ch = c & 7;
      int gm = m0 + row;
      int arow = tokens ? tokens[gm] : gm;
      uint4 v = *(const uint4*)(A + (size_t)arow * HID + k0 + ch * 8);
      *(uint4*)&As[row * GSTR + ch * 8] = v;
      int gn = n0 + row;
      uint4 w = make_uint4(0u, 0u, 0u, 0u);
      if (gn < Nreal) w = *(const uint4*)(Bm + (size_t)gn * HID + k0 + ch * 8);
      *(uint4*)&Bs[row * GSTR + ch * 8] = w;
    }
    __syncthreads();
    #pragma unroll
    for (int kk = 0; kk < 2; ++kk) {
      bf16x8 af[4], bfr[4];
      #pragma unroll
      for (int i = 0; i < 4; ++i)
        af[i] = *(const bf16x8*)&As[(wm + i * 16 + lm) * GSTR + kk * 32 + quad * 8];
      #pragma unroll
      for (int j = 0; j < 4; ++j)
        bfr[j] = *(const bf16x8*)&Bs[(wn + j * 16 + lm) * GSTR + kk * 32 + quad * 8];
      #pragma unroll
      for (int i = 0; i < 4; ++i)
        #pragma unroll
        for (int j = 0; j < 4; ++j)
          acc[i][j] = __builtin_amdgcn_mfma_f32_16x16x32_bf16(af[i], bfr[j], acc[i][j], 0, 0, 0);
    }
    __syncthreads();
  }
  // D layout: col = lane&15, row = quad*4 + reg  [measured m89/m91]
  #pragma unroll
  for (int i = 0; i < 4; ++i) {
    #pragma unroll
    for (int j = 0; j < 4; ++j) {
      #pragma unroll
      for (int r = 0; r < 4; ++r) {
        int gm = m0 + wm + i * 16 + quad * 4 + r;
        int gn = n0 + wn + j * 16 + lm;
        if (gn < Nreal)
          C[(size_t)gm * ldc + gn] = acc[i][j][r] + (bias ? bias[gn] : 0.f);
      }
    }
  }
}

// ---------------------------------------------------------------------------
// Persistent LSTM: all 256 timesteps in ONE cooperative kernel.
// 256 blocks x 256 threads; block owns 4 cells (16 w_hh rows) in REGISTERS.
// h ping-pongs through global [j][b] via agent-scope atomics (L3-coherent,
// no fences). Barrier: hierarchical counters, ONE poller per block.
// ---------------------------------------------------------------------------
__global__ __launch_bounds__(256) void lstm_persistent(
    const float* __restrict__ whh, const float* __restrict__ xproj,
    float* __restrict__ hbuf, unsigned short* __restrict__ adec,
    float* __restrict__ out_hc, unsigned* __restrict__ flags) {
  // smem dual-use (barrier-separated): phase A = h staged [k][b] pad-9
  // (1024*9 floats); phase B = partial-sum transpose [32][257] (8224 floats).
  __shared__ float smem[1024 * 9];
  __shared__ float gsum[16][8];
  const int tid = threadIdx.x;
  const int lane = tid & 63;       // k-segment: this lane covers k = kk*64+lane
  const int rq = tid >> 6;         // wave id = cell-within-block 0..3
  const int j0 = blockIdx.x * 4;   // first hidden cell of this block

  // persistent weights: rows (gate i, cell rq), element k = kk*64+lane
  float wreg[4][16];
  #pragma unroll
  for (int i = 0; i < 4; ++i)
    #pragma unroll
    for (int kk = 0; kk < 16; ++kk)
      wreg[i][kk] = whh[(size_t)(i * HID + j0 + rq) * HID + kk * 64 + lane];

  // reduce-phase mapping (tid<128): output (gate ui, cell uq, batch ub)
  const int ur = tid >> 3, ub = tid & 7;
  const int ui = ur & 3, uq = ur >> 2;
  float creg = 0.f;                // c-state for tid<32 update threads

  // barrier bookkeeping: 16 groups of 16 blocks; counters 64B apart; root
  unsigned* grp  = flags + (blockIdx.x >> 4) * 16;
  unsigned* root = flags + 512;

  for (int t = 0; t < TLEN; ++t) {
    // prefetch this thread's xproj term (read-only, normal cached load)
    float xp = 0.f;
    if (tid < 128)
      xp = xproj[(size_t)(ub * TLEN + t) * GATES + ui * HID + j0 + uq];

    // stage h_t (global transposed [j][b]) into LDS [k][b] stride 9.
    // agent-scope 8B loads: coherent (bypass stale L1/L2), L3-resident.
    const unsigned long long* hsrc =
        (const unsigned long long*)(hbuf + (size_t)(t & 1) * (BATCH * HID));
    if (t > 0) {
      #pragma unroll
      for (int it = 0; it < 16; ++it) {
        int c = tid + it * 256;                // 8B chunk 0..4095
        unsigned long long v = agent_load64(&hsrc[c]);
        int k = c >> 2, off = (c & 3) * 2;
        smem[k * 9 + off]     = __uint_as_float((unsigned)v);
        smem[k * 9 + off + 1] = __uint_as_float((unsigned)(v >> 32));
      }
    } else {
      #pragma unroll
      for (int it = 0; it < 16; ++it) {
        int c = tid + it * 256;
        int k = c >> 2, off = (c & 3) * 2;
        smem[k * 9 + off] = 0.f;
        smem[k * 9 + off + 1] = 0.f;
      }
    }
    __syncthreads();

    // 4 rows x 8 batches register outer product, k = kk*64+lane
    float acc[4][8];
    #pragma unroll
    for (int i = 0; i < 4; ++i)
      #pragma unroll
      for (int b = 0; b < 8; ++b) acc[i][b] = 0.f;
    #pragma unroll
    for (int kk = 0; kk < 16; ++kk) {
      const float* hp = &smem[(kk * 64 + lane) * 9];
      float4 ha = *(const float4*)hp;
      float4 hb = *(const float4*)(hp + 4);
      #pragma unroll
      for (int i = 0; i < 4; ++i) {
        float w = wreg[i][kk];
        acc[i][0] += w * ha.x; acc[i][1] += w * ha.y;
        acc[i][2] += w * ha.z; acc[i][3] += w * ha.w;
        acc[i][4] += w * hb.x; acc[i][5] += w * hb.y;
        acc[i][6] += w * hb.z; acc[i][7] += w * hb.w;
      }
    }
    __syncthreads();   // all h reads done before smem is reused for partials

    // column-major partial store: red[j][tid], j = gate*8+b  (stride 257)
    #pragma unroll
    for (int i = 0; i < 4; ++i)
      #pragma unroll
      for (int b = 0; b < 8; ++b)
        smem[(size_t)(i * 8 + b) * 257 + tid] = acc[i][b];
    __syncthreads();

    if (tid < 128) {
      const float* rp = &smem[(size_t)(ui * 8 + ub) * 257 + uq * 64];
      float s0 = 0.f, s1 = 0.f, s2 = 0.f, s3 = 0.f;
      #pragma unroll
      for (int c = 0; c < 16; ++c) {
        s0 += rp[c * 4 + 0]; s1 += rp[c * 4 + 1];
        s2 += rp[c * 4 + 2]; s3 += rp[c * 4 + 3];
      }
      gsum[ur][ub] = (s0 + s1) + (s2 + s3) + xp;
    }
    __syncthreads();

    if (tid < 32) {
      const int cl = tid >> 3, bb = tid & 7, j = j0 + cl;
      float gi = gsum[cl * 4 + 0][bb];
      float gf = gsum[cl * 4 + 1][bb];
      float gg = gsum[cl * 4 + 2][bb];
      float go = gsum[cl * 4 + 3][bb];
      float si = 1.f / (1.f + __expf(-gi));
      float sf = 1.f / (1.f + __expf(-gf));
      float tg = tanhf(gg);
      float so = 1.f / (1.f + __expf(-go));
      float c = sf * creg + si * tg;            // t==0: creg==0
      creg = c;
      float h = so * tanhf(c);
      // transposed h for next step: [j][b]; agent store -> visible at L3
      agent_store((unsigned*)&hbuf[(size_t)((t + 1) & 1) * (BATCH * HID) + j * 8 + bb],
                  __float_as_uint(h));
      adec[(size_t)(bb * TLEN + t) * HID + j] = f2bf(h);
      if (t == TLEN - 1) {
        out_hc[bb * HID + j] = h;                  // hT
        out_hc[BATCH * HID + bb * HID + j] = c;    // cT
      }
    }

    if (t + 1 < TLEN) {
      // __syncthreads drains vmcnt(0) in every wave -> the 32 h agent-stores
      // are acked at the coherence point before tid0 arrives below.
      __syncthreads();
      if (tid == 0) {
        unsigned prev = __hip_atomic_fetch_add(grp, 1u, __ATOMIC_RELAXED,
                                               __HIP_MEMORY_SCOPE_AGENT);
        if ((prev & 15u) == 15u)   // 16th arrival of this generation
          __hip_atomic_fetch_add(root, 1u, __ATOMIC_RELAXED,
                                 __HIP_MEMORY_SCOPE_AGENT);
        unsigned target = (unsigned)(t + 1) * 16u;
        while (agent_load(root) < target) __builtin_amdgcn_s_sleep(1);
      }
      __syncthreads();
    }
  }
}

// In-place log-softmax over rows of [2048][50257]
__global__ __launch_bounds__(512) void logsoftmax_rows(float* __restrict__ data) {
  const int row = blockIdx.x;
  float* p = data + (size_t)row * VOCABN;
  const int tid = threadIdx.x;
  float m = -INFINITY, l = 0.f;
  for (int i = tid; i < VOCABN; i += 512) {
    float x = p[i];
    float nm = fmaxf(m, x);
    l = l * __expf(m - nm) + __expf(x - nm);
    m = nm;
  }
  #pragma unroll
  for (int off = 32; off > 0; off >>= 1) {
    float m2 = __shfl_down(m, off);
    float l2 = __shfl_down(l, off);
    float nm = fmaxf(m, m2);
    l = l * __expf(m - nm) + l2 * __expf(m2 - nm);
    m = nm;
  }
  __shared__ float sm[8], sl[8];
  if ((tid & 63) == 0) { sm[tid >> 6] = m; sl[tid >> 6] = l; }
  __syncthreads();
  if (tid == 0) {
    m = sm[0]; l = sl[0];
    for (int i2 = 1; i2 < 8; ++i2) {
      float m2 = sm[i2], l2 = sl[i2];
      float nm = fmaxf(m, m2);
      l = l * __expf(m - nm) + l2 * __expf(m2 - nm);
      m = nm;
    }
    sm[0] = m; sl[0] = logf(l);
  }
  __syncthreads();
  float M = sm[0], L = sl[0];
  for (int i = tid; i < VOCABN; i += 512) p[i] = p[i] - M - L;
}

extern "C" void kernel_launch(void* const* d_in, const int* in_sizes, int n_in,
                              void* d_out, int out_size, void* d_ws, size_t ws_size,
                              hipStream_t stream) {
  const int*   x     = (const int*)d_in[0];
  const float* embW  = (const float*)d_in[1];
  const float* w_ih  = (const float*)d_in[2];
  const float* w_hh  = (const float*)d_in[3];
  const float* b_ih  = (const float*)d_in[4];
  const float* b_hh  = (const float*)d_in[5];
  const float* dec_b = (const float*)d_in[6];
  float* out = (float*)d_out;

  // ws carve
  char* ws = (char*)d_ws;
  unsigned short* emb_bf = (unsigned short*)ws;  ws += (size_t)VOCABN * HID * 2;
  unsigned short* wih_bf = (unsigned short*)ws;  ws += (size_t)GATES * HID * 2;
  float* bias_s = (float*)ws;                    ws += (size_t)GATES * 4;
  float* xproj  = (float*)ws;                    ws += (size_t)M_ROWS * GATES * 4;
  unsigned short* adec = (unsigned short*)ws;    ws += (size_t)M_ROWS * HID * 2;
  float* hbuf = (float*)ws;                      ws += (size_t)2 * BATCH * HID * 4;
  unsigned* flags = (unsigned*)ws;               ws += 4096;

  int n4emb = VOCABN * HID / 4;
  conv_f32_bf16<<<(n4emb + 255) / 256, 256, 0, stream>>>(embW, emb_bf, n4emb);
  int n4wih = GATES * HID / 4;
  conv_f32_bf16<<<(n4wih + 255) / 256, 256, 0, stream>>>(w_ih, wih_bf, n4wih);
  bias_sum_kernel<<<16, 256, 0, stream>>>(b_ih, b_hh, bias_s);
  init_flags<<<4, 256, 0, stream>>>(flags);

  // x_proj[bt][g] = emb_W[x[bt]] . w_ih[g] + (b_ih+b_hh)[g]
  gemm_bt_bf16<<<dim3(16, 32), 256, 0, stream>>>(emb_bf, wih_bf, bias_s, xproj,
                                                 x, GATES, GATES);

  // one persistent kernel = entire recurrence
  float* out_hc = out + (size_t)M_ROWS * VOCABN;
  void* kargs[] = {(void*)&w_hh, (void*)&xproj, (void*)&hbuf,
                   (void*)&adec, (void*)&out_hc, (void*)&flags};
  hipError_t ce = hipLaunchCooperativeKernel((void*)lstm_persistent,
                                             dim3(256), dim3(256), kargs, 0, stream);
  if (ce != hipSuccess) {
    // fallback: plain launch; 256 blocks x 256 thr (37KB LDS) = 1 block/CU,
    // naturally co-resident on an idle 256-CU device
    lstm_persistent<<<dim3(256), dim3(256), 0, stream>>>(w_hh, xproj, hbuf,
                                                         adec, out_hc, flags);
  }

  // logits[bt][v] = h[bt] . emb_W[v] + dec_b[v]
  gemm_bt_bf16<<<dim3(16, 393), 256, 0, stream>>>(adec, emb_bf, dec_b, out,
                                                  nullptr, VOCABN, VOCABN);

  logsoftmax_rows<<<2048, 512, 0, stream>>>(out);
}

// Round 3
// 4159.399 us; speedup vs baseline: 3.2105x; 1.1689x over previous
//
#include <hip/hip_runtime.h>

typedef short bf16x8 __attribute__((ext_vector_type(8)));
typedef float f32x4 __attribute__((ext_vector_type(4)));

#define HID   1024
#define BATCH 8
#define TLEN  256
#define VOCABN 50257
#define GATES 4096   // 4*HID
#define M_ROWS 2048  // B*T
#define HSLOTS 16    // h ring slots (power of 2)
#define SENT 0x7fc00000u  // qNaN sentinel: h=o*tanh(c) is finite, |h|<1

__device__ __forceinline__ unsigned short f2bf(float x) {
  unsigned int u = __float_as_uint(x);
  unsigned int r = (u + 0x7fffu + ((u >> 16) & 1u)) >> 16;
  return (unsigned short)r;
}

// ---- agent-scope (cross-XCD coherent) primitives: no fences, no L2 flush ----
__device__ __forceinline__ unsigned long long agent_load64(const unsigned long long* p) {
  return __hip_atomic_load(p, __ATOMIC_RELAXED, __HIP_MEMORY_SCOPE_AGENT);
}
__device__ __forceinline__ void agent_store(unsigned* p, unsigned v) {
  __hip_atomic_store(p, v, __ATOMIC_RELAXED, __HIP_MEMORY_SCOPE_AGENT);
}

__global__ void conv_f32_bf16(const float* __restrict__ src,
                              unsigned short* __restrict__ dst, int n4) {
  int i = blockIdx.x * 256 + threadIdx.x;
  if (i >= n4) return;
  float4 v = ((const float4*)src)[i];
  ushort4 o;
  o.x = f2bf(v.x); o.y = f2bf(v.y); o.z = f2bf(v.z); o.w = f2bf(v.w);
  ((ushort4*)dst)[i] = o;
}

__global__ void bias_sum_kernel(const float* __restrict__ a,
                                const float* __restrict__ b,
                                float* __restrict__ o) {
  int i = blockIdx.x * 256 + threadIdx.x;
  if (i < GATES) o[i] = a[i] + b[i];
}

// slot 0 = zeros (h_0), slots 1..15 = sentinel. 16 slots x 8192 floats.
__global__ void init_hseq(float* __restrict__ hseq) {
  int i = blockIdx.x * 256 + threadIdx.x;       // uint4 index, 32768 total
  unsigned fill = ((i * 4) < BATCH * HID) ? 0u : SENT;
  uint4 v = make_uint4(fill, fill, fill, fill);
  ((uint4*)hseq)[i] = v;
}

// C[m][n] = sum_k A[m,k]*B[n,k] + bias[n].  A,B bf16 K-major, C fp32.
// tokens!=nullptr => A row m is table row tokens[m] (embedding gather).
#define GSTR 72  // LDS row stride in bf16 (64 data + 8 pad) -> conflict-free b128 frag reads

__global__ __launch_bounds__(256) void gemm_bt_bf16(
    const unsigned short* __restrict__ A, const unsigned short* __restrict__ Bm,
    const float* __restrict__ bias, float* __restrict__ C,
    const int* __restrict__ tokens, int ldc, int Nreal) {
  __shared__ unsigned short As[128 * GSTR];
  __shared__ unsigned short Bs[128 * GSTR];
  const int tid = threadIdx.x;
  const int m0 = blockIdx.x * 128;
  const int n0 = blockIdx.y * 128;
  const int wid = tid >> 6, lane = tid & 63;
  const int wm = (wid & 1) * 64, wn = (wid >> 1) * 64;
  const int lm = lane & 15, quad = lane >> 4;

  f32x4 acc[4][4];
  #pragma unroll
  for (int i = 0; i < 4; ++i)
    #pragma unroll
    for (int j = 0; j < 4; ++j) acc[i][j] = (f32x4){0.f, 0.f, 0.f, 0.f};

  for (int k0 = 0; k0 < HID; k0 += 64) {
    #pragma unroll
    for (int it = 0; it < 4; ++it) {           // 1024 16B-chunks per tile, 256 thr
      int c = tid + it * 256;
      int row = c >> 3, ch = c & 7;
      int gm = m0 + row;
      int arow = tokens ? tokens[gm] : gm;
      uint4 v = *(const uint4*)(A + (size_t)arow * HID + k0 + ch * 8);
      *(uint4*)&As[row * GSTR + ch * 8] = v;
      int gn = n0 + row;
      uint4 w = make_uint4(0u, 0u, 0u, 0u);
      if (gn < Nreal) w = *(const uint4*)(Bm + (size_t)gn * HID + k0 + ch * 8);
      *(uint4*)&Bs[row * GSTR + ch * 8] = w;
    }
    __syncthreads();
    #pragma unroll
    for (int kk = 0; kk < 2; ++kk) {
      bf16x8 af[4], bfr[4];
      #pragma unroll
      for (int i = 0; i < 4; ++i)
        af[i] = *(const bf16x8*)&As[(wm + i * 16 + lm) * GSTR + kk * 32 + quad * 8];
      #pragma unroll
      for (int j = 0; j < 4; ++j)
        bfr[j] = *(const bf16x8*)&Bs[(wn + j * 16 + lm) * GSTR + kk * 32 + quad * 8];
      #pragma unroll
      for (int i = 0; i < 4; ++i)
        #pragma unroll
        for (int j = 0; j < 4; ++j)
          acc[i][j] = __builtin_amdgcn_mfma_f32_16x16x32_bf16(af[i], bfr[j], acc[i][j], 0, 0, 0);
    }
    __syncthreads();
  }
  // D layout: col = lane&15, row = quad*4 + reg  [measured m89/m91]
  #pragma unroll
  for (int i = 0; i < 4; ++i) {
    #pragma unroll
    for (int j = 0; j < 4; ++j) {
      #pragma unroll
      for (int r = 0; r < 4; ++r) {
        int gm = m0 + wm + i * 16 + quad * 4 + r;
        int gn = n0 + wn + j * 16 + lm;
        if (gn < Nreal)
          C[(size_t)gm * ldc + gn] = acc[i][j][r] + (bias ? bias[gn] : 0.f);
      }
    }
  }
}

// ---------------------------------------------------------------------------
// Persistent LSTM, BARRIER-FREE self-timed dataflow.
// 256 blocks x 256 threads; block owns 4 cells (16 w_hh rows) in REGISTERS.
// h for step t lives in ring slot hseq[t%16] ([j][b] layout, fp32).
// Producers: fire-and-forget agent stores. Consumers: poll data until
// != qNaN sentinel. Slot (t-1)%16 is re-poisoned at step t by block
// (t-1)%256 — provably race-free (consuming h[t] implies every block
// consumed h[t-1]; slot not rewritten for another 14 steps).
// ---------------------------------------------------------------------------
__global__ __launch_bounds__(256) void lstm_persistent(
    const float* __restrict__ whh, const float* __restrict__ xproj,
    float* __restrict__ hseq, unsigned short* __restrict__ adec,
    float* __restrict__ out_hc) {
  // smem dual-use (barrier-separated): phase A = h staged [k][b] pad-9
  // (1024*9 floats); phase B = partial-sum transpose [32][257] (8224 floats).
  __shared__ float smem[1024 * 9];
  __shared__ float gsum[16][8];
  const int tid = threadIdx.x;
  const int lane = tid & 63;       // k-segment: this lane covers k = kk*64+lane
  const int rq = tid >> 6;         // wave id = cell-within-block 0..3
  const int j0 = blockIdx.x * 4;   // first hidden cell of this block

  // persistent weights: rows (gate i, cell rq), element k = kk*64+lane
  float wreg[4][16];
  #pragma unroll
  for (int i = 0; i < 4; ++i)
    #pragma unroll
    for (int kk = 0; kk < 16; ++kk)
      wreg[i][kk] = whh[(size_t)(i * HID + j0 + rq) * HID + kk * 64 + lane];

  // reduce-phase mapping (tid<128): output (gate ui, cell uq, batch ub)
  const int ur = tid >> 3, ub = tid & 7;
  const int ui = ur & 3, uq = ur >> 2;
  float creg = 0.f;                // c-state for tid<32 update threads

  for (int t = 0; t < TLEN; ++t) {
    // prefetch this thread's xproj term (read-only, normal cached load)
    float xp = 0.f;
    if (tid < 128)
      xp = xproj[(size_t)(ub * TLEN + t) * GATES + ui * HID + j0 + uq];

    // ---- consume h_t: poll ring slot until all sentinels replaced ----
    const unsigned long long* hsrc =
        (const unsigned long long*)(hseq + (size_t)(t & (HSLOTS - 1)) * (BATCH * HID));
    unsigned long long v[16];
    #pragma unroll
    for (int it = 0; it < 16; ++it)           // 16 pipelined 8B coherent loads
      v[it] = agent_load64(&hsrc[tid + it * 256]);
    #pragma unroll
    for (int it = 0; it < 16; ++it) {
      unsigned long long x = v[it];
      while ((unsigned)x == SENT || (unsigned)(x >> 32) == SENT) {
        __builtin_amdgcn_s_sleep(1);
        x = agent_load64(&hsrc[tid + it * 256]);
      }
      int c = tid + it * 256;                 // 8B chunk: j = c>>2, b = (c&3)*2
      int k = c >> 2, off = (c & 3) * 2;
      smem[k * 9 + off]     = __uint_as_float((unsigned)x);
      smem[k * 9 + off + 1] = __uint_as_float((unsigned)(x >> 32));
    }
    __syncthreads();

    // re-poison duty: one block per step, fire-and-forget (safe: all blocks
    // have consumed h[t-1] once any block consumed h[t])
    if (t >= 1 && ((unsigned)(t - 1) & 255u) == blockIdx.x) {
      unsigned* ps = (unsigned*)(hseq + (size_t)((t - 1) & (HSLOTS - 1)) * (BATCH * HID));
      #pragma unroll
      for (int it = 0; it < 32; ++it)
        agent_store(&ps[tid + it * 256], SENT);
    }

    // 4 rows x 8 batches register outer product, k = kk*64+lane
    float acc[4][8];
    #pragma unroll
    for (int i = 0; i < 4; ++i)
      #pragma unroll
      for (int b = 0; b < 8; ++b) acc[i][b] = 0.f;
    #pragma unroll
    for (int kk = 0; kk < 16; ++kk) {
      const float* hp = &smem[(kk * 64 + lane) * 9];
      float4 ha = *(const float4*)hp;
      float4 hb = *(const float4*)(hp + 4);
      #pragma unroll
      for (int i = 0; i < 4; ++i) {
        float w = wreg[i][kk];
        acc[i][0] += w * ha.x; acc[i][1] += w * ha.y;
        acc[i][2] += w * ha.z; acc[i][3] += w * ha.w;
        acc[i][4] += w * hb.x; acc[i][5] += w * hb.y;
        acc[i][6] += w * hb.z; acc[i][7] += w * hb.w;
      }
    }
    __syncthreads();   // all h reads done before smem is reused for partials

    // column-major partial store: red[j][tid], j = gate*8+b  (stride 257)
    #pragma unroll
    for (int i = 0; i < 4; ++i)
      #pragma unroll
      for (int b = 0; b < 8; ++b)
        smem[(size_t)(i * 8 + b) * 257 + tid] = acc[i][b];
    __syncthreads();

    if (tid < 128) {
      const float* rp = &smem[(size_t)(ui * 8 + ub) * 257 + uq * 64];
      float s0 = 0.f, s1 = 0.f, s2 = 0.f, s3 = 0.f;
      #pragma unroll
      for (int c = 0; c < 16; ++c) {
        s0 += rp[c * 4 + 0]; s1 += rp[c * 4 + 1];
        s2 += rp[c * 4 + 2]; s3 += rp[c * 4 + 3];
      }
      gsum[ur][ub] = (s0 + s1) + (s2 + s3) + xp;
    }
    __syncthreads();

    if (tid < 32) {
      const int cl = tid >> 3, bb = tid & 7, j = j0 + cl;
      float gi = gsum[cl * 4 + 0][bb];
      float gf = gsum[cl * 4 + 1][bb];
      float gg = gsum[cl * 4 + 2][bb];
      float go = gsum[cl * 4 + 3][bb];
      float si = 1.f / (1.f + __expf(-gi));
      float sf = 1.f / (1.f + __expf(-gf));
      float tg = tanhf(gg);
      float so = 1.f / (1.f + __expf(-go));
      float c = sf * creg + si * tg;            // t==0: creg==0
      creg = c;
      float h = so * tanhf(c);
      // produce h_{t+1}: fire-and-forget agent store into next ring slot
      if (t + 1 < TLEN)
        agent_store((unsigned*)&hseq[(size_t)((t + 1) & (HSLOTS - 1)) * (BATCH * HID) + j * 8 + bb],
                    __float_as_uint(h));
      adec[(size_t)(bb * TLEN + t) * HID + j] = f2bf(h);
      if (t == TLEN - 1) {
        out_hc[bb * HID + j] = h;                  // hT
        out_hc[BATCH * HID + bb * HID + j] = c;    // cT
      }
    }
    __syncthreads();   // protect smem phase A of next iteration
  }
}

// In-place log-softmax over rows of [2048][50257]
__global__ __launch_bounds__(512) void logsoftmax_rows(float* __restrict__ data) {
  const int row = blockIdx.x;
  float* p = data + (size_t)row * VOCABN;
  const int tid = threadIdx.x;
  float m = -INFINITY, l = 0.f;
  for (int i = tid; i < VOCABN; i += 512) {
    float x = p[i];
    float nm = fmaxf(m, x);
    l = l * __expf(m - nm) + __expf(x - nm);
    m = nm;
  }
  #pragma unroll
  for (int off = 32; off > 0; off >>= 1) {
    float m2 = __shfl_down(m, off);
    float l2 = __shfl_down(l, off);
    float nm = fmaxf(m, m2);
    l = l * __expf(m - nm) + l2 * __expf(m2 - nm);
    m = nm;
  }
  __shared__ float sm[8], sl[8];
  if ((tid & 63) == 0) { sm[tid >> 6] = m; sl[tid >> 6] = l; }
  __syncthreads();
  if (tid == 0) {
    m = sm[0]; l = sl[0];
    for (int i2 = 1; i2 < 8; ++i2) {
      float m2 = sm[i2], l2 = sl[i2];
      float nm = fmaxf(m, m2);
      l = l * __expf(m - nm) + l2 * __expf(m2 - nm);
      m = nm;
    }
    sm[0] = m; sl[0] = logf(l);
  }
  __syncthreads();
  float M = sm[0], L = sl[0];
  for (int i = tid; i < VOCABN; i += 512) p[i] = p[i] - M - L;
}

extern "C" void kernel_launch(void* const* d_in, const int* in_sizes, int n_in,
                              void* d_out, int out_size, void* d_ws, size_t ws_size,
                              hipStream_t stream) {
  const int*   x     = (const int*)d_in[0];
  const float* embW  = (const float*)d_in[1];
  const float* w_ih  = (const float*)d_in[2];
  const float* w_hh  = (const float*)d_in[3];
  const float* b_ih  = (const float*)d_in[4];
  const float* b_hh  = (const float*)d_in[5];
  const float* dec_b = (const float*)d_in[6];
  float* out = (float*)d_out;

  // ws carve
  char* ws = (char*)d_ws;
  unsigned short* emb_bf = (unsigned short*)ws;  ws += (size_t)VOCABN * HID * 2;
  unsigned short* wih_bf = (unsigned short*)ws;  ws += (size_t)GATES * HID * 2;
  float* bias_s = (float*)ws;                    ws += (size_t)GATES * 4;
  float* xproj  = (float*)ws;                    ws += (size_t)M_ROWS * GATES * 4;
  unsigned short* adec = (unsigned short*)ws;    ws += (size_t)M_ROWS * HID * 2;
  float* hseq = (float*)ws;                      ws += (size_t)HSLOTS * BATCH * HID * 4;

  int n4emb = VOCABN * HID / 4;
  conv_f32_bf16<<<(n4emb + 255) / 256, 256, 0, stream>>>(embW, emb_bf, n4emb);
  int n4wih = GATES * HID / 4;
  conv_f32_bf16<<<(n4wih + 255) / 256, 256, 0, stream>>>(w_ih, wih_bf, n4wih);
  bias_sum_kernel<<<16, 256, 0, stream>>>(b_ih, b_hh, bias_s);
  init_hseq<<<HSLOTS * BATCH * HID / 1024, 256, 0, stream>>>(hseq);

  // x_proj[bt][g] = emb_W[x[bt]] . w_ih[g] + (b_ih+b_hh)[g]
  gemm_bt_bf16<<<dim3(16, 32), 256, 0, stream>>>(emb_bf, wih_bf, bias_s, xproj,
                                                 x, GATES, GATES);

  // one persistent kernel = entire recurrence (barrier-free dataflow)
  float* out_hc = out + (size_t)M_ROWS * VOCABN;
  void* kargs[] = {(void*)&w_hh, (void*)&xproj, (void*)&hseq,
                   (void*)&adec, (void*)&out_hc};
  hipError_t ce = hipLaunchCooperativeKernel((void*)lstm_persistent,
                                             dim3(256), dim3(256), kargs, 0, stream);
  if (ce != hipSuccess) {
    // fallback: plain launch; 256 blocks x 256 thr (37KB LDS) = 1 block/CU,
    // naturally co-resident on an idle 256-CU device
    lstm_persistent<<<dim3(256), dim3(256), 0, stream>>>(w_hh, xproj, hseq,
                                                         adec, out_hc);
  }

  // logits[bt][v] = h[bt] . emb_W[v] + dec_b[v]
  gemm_bt_bf16<<<dim3(16, 393), 256, 0, stream>>>(adec, emb_bf, dec_b, out,
                                                  nullptr, VOCABN, VOCABN);

  logsoftmax_rows<<<2048, 512, 0, stream>>>(out);
}